// Round 9
// baseline (291.813 us; speedup 1.0000x reference)
//
#include <hip/hip_runtime.h>
#include <hip/hip_bf16.h>
#include <stdint.h>

typedef __attribute__((ext_vector_type(8))) __bf16 bf8v;   // MFMA A/B frag: 8 bf16 = 4 VGPR
typedef __attribute__((ext_vector_type(4))) float f4v;     // 16x16 MFMA C/D frag
typedef __attribute__((ext_vector_type(16))) float f16v;   // 32x32 MFMA C/D frag

#define L2E 1.44269504088896f

// fp32 -> bf16 round-to-nearest-even (bit pattern as ushort)
__device__ __forceinline__ unsigned short f2bf(float f) {
  union { float f; unsigned u; } v; v.f = f;
  unsigned r = v.u + 0x7fffu + ((v.u >> 16) & 1u);
  return (unsigned short)(r >> 16);
}

// pack two fp32 -> dword of two RNE bf16 (low = f0), HW v_cvt_pk_bf16_f32 path
__device__ __forceinline__ unsigned pk2bf(float f0, float f1) {
  union { __hip_bfloat162 h; unsigned u; } c;
  c.h = __float22bfloat162_rn(make_float2(f0, f1));
  return c.u;
}

// 2^x via v_exp_f32
__device__ __forceinline__ float exp2_hw(float x) {
  return __builtin_amdgcn_exp2f(x);
}

// async global->LDS, 16B per lane; LDS dest = wave-uniform base + lane*16
__device__ __forceinline__ void gl_lds16(const void* g, void* l) {
  __builtin_amdgcn_global_load_lds(
      (__attribute__((address_space(1))) void*)(g),
      (__attribute__((address_space(3))) void*)(l), 16, 0, 0);
}

// ---------------- fused prep: cast x -> bf16  +  weight transpose/cast ----------------
__global__ void prep_kernel(const float* __restrict__ x,
                            const float* __restrict__ w_in,
                            const float* __restrict__ w_out,
                            unsigned short* __restrict__ xb,
                            unsigned short* __restrict__ wiT,
                            unsigned short* __restrict__ woT) {
  __shared__ float tile[32][33];
  int bx = blockIdx.x;
  if (bx < 8192) {
    int i = bx * 256 + threadIdx.x;
    float4 v = ((const float4*)x)[i];
    ushort4 o;
    o.x = f2bf(v.x); o.y = f2bf(v.y); o.z = f2bf(v.z); o.w = f2bf(v.w);
    ((ushort4*)xb)[i] = o;
    return;
  }
  int idx = bx - 8192;              // 0..4095 -> (128 x, 32 y)
  int bxx = idx & 127, byy = idx >> 7;
  const float* in; unsigned short* out; int C, c0;
  if (bxx < 96) { in = w_in;  out = wiT; C = 3072; c0 = bxx * 32; }
  else          { in = w_out; out = woT; C = 1024; c0 = (bxx - 96) * 32; }
  int r0 = byy * 32;
  int tx = threadIdx.x & 31, ty = threadIdx.x >> 5;
#pragma unroll
  for (int j = 0; j < 4; ++j)
    tile[ty + 8 * j][tx] = in[(size_t)(r0 + ty + 8 * j) * C + c0 + tx];
  __syncthreads();
#pragma unroll
  for (int j = 0; j < 4; ++j)
    out[(size_t)(c0 + ty + 8 * j) * 1024 + r0 + tx] = f2bf(tile[tx][ty + 8 * j]);
}

// ---------------- GEMM1: 256x256, BK=64, 8-phase pipeline (r8-verified loop) ----------------
// Epilogue v2: V columns (>=2048) now go through an LDS transpose (As region is
// dead after the main loop) and store as 512B-coalesced uint4 lines into
// vtg[b][h][d][tok] — replaces the 8B/4KB-stride scatter (est. ~10us, r6->r7).
__global__ __launch_bounds__(512, 2) void gemm1_8ph(
    const unsigned short* __restrict__ A,
    const unsigned short* __restrict__ BT,
    const float* __restrict__ bias,
    unsigned short* __restrict__ qk,
    unsigned short* __restrict__ vtg,
    int K, int nbx, float scale) {
  __shared__ __align__(16) unsigned short As[2][256 * 64];
  __shared__ __align__(16) unsigned short Bs[2][256 * 64];
  const int tid = threadIdx.x;
  const int wave = tid >> 6, lane = tid & 63;
  const int lo = lane & 15, hi = lane >> 4;
  const int wm = wave >> 2, wn = wave & 3;   // 2M x 4N

  const int cpx = gridDim.x >> 3;
  const int s = (blockIdx.x & 7) * cpx + (blockIdx.x >> 3);
  const int by = s / nbx, bx = s - by * nbx;
  const int m0 = by * 256, n0 = bx * 256;

  const int srow = lane >> 3;
  const int scol = (((lane & 7) ^ (srow & 7)) * 8);
  const unsigned short* gA = A + (size_t)(m0 + wave * 8 + srow) * K + scol;
  const unsigned short* gB = BT + (size_t)(n0 + wave * 8 + srow) * K + scol;

  const int csw0 = ((hi ^ (lo & 7)) * 8);
  const int csw1 = (((4 + hi) ^ (lo & 7)) * 8);
  const int rA = wm * 128;   // + frag*16 + lo
  const int rB = wn * 64;    // + fn*16 + lo

  f4v acc[8][4] = {};
  const int nt = K >> 6;

  auto stageA = [&](int t, int buf, int half) {
    const unsigned short* g = gA + (size_t)(half * 128) * K + t * 64;
#pragma unroll
    for (int j = 0; j < 2; ++j)
      gl_lds16(g + (size_t)(j * 64) * K, &As[buf][(half * 128 + j * 64 + wave * 8) * 64]);
  };
  auto stageB = [&](int t, int buf, int half) {
    const unsigned short* g = gB + (size_t)(half * 128) * K + t * 64;
#pragma unroll
    for (int j = 0; j < 2; ++j)
      gl_lds16(g + (size_t)(j * 64) * K, &Bs[buf][(half * 128 + j * 64 + wave * 8) * 64]);
  };

  stageA(0, 0, 0); stageA(0, 0, 1);
  stageB(0, 0, 0); stageB(0, 0, 1);
  if (nt > 1) { stageB(1, 1, 0); stageB(1, 1, 1); }
  asm volatile("s_waitcnt vmcnt(4)" ::: "memory");
  __builtin_amdgcn_sched_barrier(0);
  __builtin_amdgcn_s_barrier();

  for (int t = 0; t < nt; ++t) {
    const int c = t & 1;
    bf8v b[4][2];
#pragma unroll
    for (int p = 0; p < 4; ++p) {
      if (p == 0) {
#pragma unroll
        for (int fn = 0; fn < 4; ++fn) {
          b[fn][0] = *(const bf8v*)&Bs[c][(rB + fn * 16 + lo) * 64 + csw0];
          b[fn][1] = *(const bf8v*)&Bs[c][(rB + fn * 16 + lo) * 64 + csw1];
        }
      }
      bf8v a[2][2];
#pragma unroll
      for (int i = 0; i < 2; ++i) {
        a[i][0] = *(const bf8v*)&As[c][(rA + (p * 2 + i) * 16 + lo) * 64 + csw0];
        a[i][1] = *(const bf8v*)&As[c][(rA + (p * 2 + i) * 16 + lo) * 64 + csw1];
      }
      if (p < 2) {
        if (t + 1 < nt) stageA(t + 1, c ^ 1, p);
      } else {
        if (t + 2 < nt) stageB(t + 2, c, p - 2);
      }
      if (p == 3 && t + 1 < nt) {
        if (t + 2 < nt) asm volatile("s_waitcnt vmcnt(4)" ::: "memory");
        else            asm volatile("s_waitcnt vmcnt(0)" ::: "memory");
        __builtin_amdgcn_sched_barrier(0);
      }
      __builtin_amdgcn_s_barrier();
      __builtin_amdgcn_s_setprio(1);
#pragma unroll
      for (int ks = 0; ks < 2; ++ks)
#pragma unroll
        for (int i = 0; i < 2; ++i)
#pragma unroll
          for (int fn = 0; fn < 4; ++fn)
            acc[p * 2 + i][fn] = __builtin_amdgcn_mfma_f32_16x16x32_bf16(
                a[i][ks], b[fn][ks], acc[p * 2 + i][fn], 0, 0, 0);
      __builtin_amdgcn_s_setprio(0);
      __builtin_amdgcn_s_barrier();
    }
  }

  // ---- epilogue
  if (n0 < 2048) {
    // Q/K -> qk (stride 2048); Q cols scaled by log2(e)
#pragma unroll
    for (int i = 0; i < 8; ++i) {
#pragma unroll
      for (int j = 0; j < 4; ++j) {
        const int col = n0 + wn * 64 + j * 16 + lo;
        const int row0 = m0 + wm * 128 + i * 16 + hi * 4;
        const float bb = bias[col];
        const float sc = (col < 1024) ? scale : 1.0f;
#pragma unroll
        for (int r = 0; r < 4; ++r)
          qk[(size_t)(row0 + r) * 2048 + col] = f2bf((acc[i][j][r] + bb) * sc);
      }
    }
  } else {
    // V block: LDS transpose (As region dead), one head (64 cols) per pass,
    // then 512B-coalesced uint4 stores into vtg[b][h][d][tok].
    unsigned short* T = &As[0][0];          // [64 cols][264] shorts = 33.8 KB
    const int hh0 = (n0 - 2048) >> 6;       // first head of this block (4 heads)
    const int bbt = m0 >> 11, tokbase = m0 & 2047;
#pragma unroll 1
    for (int g = 0; g < 4; ++g) {
      __syncthreads();                       // main-loop/previous-pass LDS reads done
      if (wn == g) {                         // 2 writer waves (wm 0,1)
#pragma unroll
        for (int i = 0; i < 8; ++i)
#pragma unroll
          for (int j = 0; j < 4; ++j) {
            const int col = j * 16 + lo;               // 0..63 within head
            const int row0 = wm * 128 + i * 16 + hi * 4;  // tok-in-block, mult of 4
            const float bb = bias[n0 + wn * 64 + j * 16 + lo];
            uint2 w;
            w.x = pk2bf(acc[i][j][0] + bb, acc[i][j][1] + bb);
            w.y = pk2bf(acc[i][j][2] + bb, acc[i][j][3] + bb);
            *(uint2*)&T[col * 264 + row0] = w;
          }
      }
      __syncthreads();
      // all 512 threads: [64 d][256 tok] -> vtg rows, 64B per thread
      {
        const int d = tid >> 3, tk = (tid & 7) * 32;
        unsigned short* dst =
            vtg + ((((size_t)bbt * 16 + hh0 + g) * 64 + d) * 2048) + tokbase + tk;
        const unsigned short* srcl = &T[d * 264 + tk];
#pragma unroll
        for (int q4 = 0; q4 < 4; ++q4)
          *(uint4*)(dst + q4 * 8) = *(const uint4*)(srcl + q4 * 8);
      }
    }
  }
}

// ---------------- GEMM2: 256x128 tile, BK=64, 2-phase deep pipeline (round-5 verified) ----------------
__global__ __launch_bounds__(512, 2) void gemm2k(
    const unsigned short* __restrict__ A,
    const unsigned short* __restrict__ BT,
    const float* __restrict__ bias,
    float* __restrict__ C,
    int N, int K, int nbx) {
  __shared__ __align__(16) unsigned short As[2][256 * 64];
  __shared__ __align__(16) unsigned short Bs[2][128 * 64];
  const int tid = threadIdx.x;
  const int wave = tid >> 6, lane = tid & 63;
  const int lo = lane & 15, hi = lane >> 4;
  const int wm = wave >> 1, wn = wave & 1;

  const int cpx = gridDim.x >> 3;
  const int s = (blockIdx.x & 7) * cpx + (blockIdx.x >> 3);
  const int by = s / nbx, bx = s - by * nbx;
  const int m0 = by * 256, n0 = bx * 128;

  const int srow = lane >> 3;
  const int scol = (((lane & 7) ^ (srow & 7)) * 8);
  const unsigned short* gA = A + (size_t)(m0 + wave * 8 + srow) * K + scol;
  const unsigned short* gB = BT + (size_t)(n0 + wave * 8 + srow) * K + scol;

  const int csw0 = ((hi ^ (lo & 7)) * 8);
  const int csw1 = (((4 + hi) ^ (lo & 7)) * 8);
  const int rA = wm * 64;
  const int rB = wn * 64;

  f4v acc[4][4] = {};
  const int nt = K >> 6;

#pragma unroll
  for (int j = 0; j < 4; ++j)
    gl_lds16(gA + (size_t)(j * 64) * K, &As[0][(j * 64 + wave * 8) * 64]);
#pragma unroll
  for (int j = 0; j < 2; ++j)
    gl_lds16(gB + (size_t)(j * 64) * K, &Bs[0][(j * 64 + wave * 8) * 64]);

  for (int t = 0; t < nt; ++t) {
    const int c = t & 1;
    __builtin_amdgcn_s_barrier();
    __builtin_amdgcn_sched_barrier(0);
    if (t + 1 < nt) {
      const unsigned short* gA1 = gA + (size_t)(t + 1) * 64;
      const unsigned short* gB1 = gB + (size_t)(t + 1) * 64;
#pragma unroll
      for (int j = 0; j < 4; ++j)
        gl_lds16(gA1 + (size_t)(j * 64) * K, &As[c ^ 1][(j * 64 + wave * 8) * 64]);
#pragma unroll
      for (int j = 0; j < 2; ++j)
        gl_lds16(gB1 + (size_t)(j * 64) * K, &Bs[c ^ 1][(j * 64 + wave * 8) * 64]);
      asm volatile("s_waitcnt vmcnt(6)" ::: "memory");
    } else {
      asm volatile("s_waitcnt vmcnt(0)" ::: "memory");
    }
    __builtin_amdgcn_sched_barrier(0);
    __builtin_amdgcn_s_barrier();
    __builtin_amdgcn_sched_barrier(0);

    bf8v b[4][2];
#pragma unroll
    for (int fn = 0; fn < 4; ++fn) {
      b[fn][0] = *(const bf8v*)&Bs[c][(rB + fn * 16 + lo) * 64 + csw0];
      b[fn][1] = *(const bf8v*)&Bs[c][(rB + fn * 16 + lo) * 64 + csw1];
    }
#pragma unroll
    for (int p = 0; p < 2; ++p) {
      bf8v a[2][2];
#pragma unroll
      for (int i = 0; i < 2; ++i) {
        a[i][0] = *(const bf8v*)&As[c][(rA + (p * 2 + i) * 16 + lo) * 64 + csw0];
        a[i][1] = *(const bf8v*)&As[c][(rA + (p * 2 + i) * 16 + lo) * 64 + csw1];
      }
      __builtin_amdgcn_s_setprio(1);
#pragma unroll
      for (int ks = 0; ks < 2; ++ks)
#pragma unroll
        for (int i = 0; i < 2; ++i)
#pragma unroll
          for (int fn = 0; fn < 4; ++fn)
            acc[p * 2 + i][fn] = __builtin_amdgcn_mfma_f32_16x16x32_bf16(
                a[i][ks], b[fn][ks], acc[p * 2 + i][fn], 0, 0, 0);
      __builtin_amdgcn_s_setprio(0);
    }
  }

#pragma unroll
  for (int i = 0; i < 4; ++i) {
#pragma unroll
    for (int r = 0; r < 4; ++r) {
      int row = m0 + wm * 64 + i * 16 + hi * 4 + r;
#pragma unroll
      for (int j = 0; j < 4; ++j) {
        int col = n0 + wn * 64 + j * 16 + lo;
        C[(size_t)row * N + col] = acc[i][j][r] + bias[col];
      }
    }
  }
}

// ---------------- flash attention v9: 32x32x16 MFMA + in-register P (T12) ----------------
// Per-wave per-kt vs v7: MFMA instr 72->40, LDS ops 40->16+4 (P round-trip deleted),
// +16 v_permlane32_swap. S^T C/D (col=q=lane&31, row=key=(r&3)+8(r>>2)+4(lane>>5))
// puts even key-quads in lanes<32, odd in lanes>=32; permlane32_swap(a,bb) of the
// cvt_pk'd quad dwords yields the PV A-fragment for both halves directly.
// K/V staging + single-barrier dbuf protocol byte-identical to v7 (verified 3x).
#define FSTR 72   // LDS row stride (shorts): 64 payload + 8 pad

__global__ __launch_bounds__(256, 2) void flash_attn(
    const unsigned short* __restrict__ qk,    // [8192][2048]: Q cols 0..1023, K cols 1024..2047
    const unsigned short* __restrict__ vtg,   // [b*16+h][64][2048]
    unsigned short* __restrict__ y) {
  __shared__ __align__(16) unsigned short Kt[2][64 * FSTR]; // K tiles [key][d], dbuf
  __shared__ __align__(16) unsigned short Vt[2][64 * FSTR]; // V^T tiles [d][key], dbuf
  const int tid = threadIdx.x;
  const int wave = tid >> 6, lane = tid & 63;
  const int lq = lane & 31, hf = lane >> 5;

  // XCD swizzle: 512 blocks; XCD c gets one b, 8 heads (~3MB QK/V -> L2-resident)
  const int lin = blockIdx.x;
  const int swz = (lin & 7) * 64 + (lin >> 3);
  const int q0 = (swz & 7) << 8;
  const int h  = (swz >> 3) & 15;
  const int b  = swz >> 7;

  const size_t base = (size_t)b * 2048 * 2048;
  const int qoff = h * 64, koff = 1024 + h * 64;
  const unsigned short* vsrc = vtg + (size_t)(b * 16 + h) * 64 * 2048;
  const unsigned short* kg = qk + base + koff;

  // ---- K/V staging: reg-held prefetch (v7 protocol)
  const int m_st = tid >> 3, c_st = tid & 7;
  float4 rk0, rk1, rv0, rv1;
  auto kv_load = [&](int kt) {
    const int mb = kt * 64;
    rk0 = *(const float4*)(kg + (size_t)(mb + m_st) * 2048 + c_st * 8);
    rk1 = *(const float4*)(kg + (size_t)(mb + m_st + 32) * 2048 + c_st * 8);
    rv0 = *(const float4*)(vsrc + (size_t)m_st * 2048 + mb + c_st * 8);
    rv1 = *(const float4*)(vsrc + (size_t)(m_st + 32) * 2048 + mb + c_st * 8);
  };
  auto kv_write = [&](int buf) {
    *(float4*)&Kt[buf][m_st * FSTR + c_st * 8] = rk0;
    *(float4*)&Kt[buf][(m_st + 32) * FSTR + c_st * 8] = rk1;
    *(float4*)&Vt[buf][m_st * FSTR + c_st * 8] = rv0;
    *(float4*)&Vt[buf][(m_st + 32) * FSTR + c_st * 8] = rv1;
  };

  kv_load(0);

  // Q B-operand frags direct from global, once per block (Q pre-scaled by log2e).
  // 32x32x16 B layout: lane l holds B[k = (l>>5)*8 + j][col = q = l&31].
  bf8v bq[2][4];  // [qt][ks], ks = d/16
#pragma unroll
  for (int qt = 0; qt < 2; ++qt)
#pragma unroll
    for (int ks = 0; ks < 4; ++ks)
      bq[qt][ks] = *(const bf8v*)(qk + base +
          (size_t)(q0 + wave * 64 + qt * 32 + lq) * 2048 + qoff + ks * 16 + hf * 8);

  f16v O[2][2] = {};       // [qt][dt]: C/D col = d = dt*32+lq, row = q-in-tile
  f16v acc_l[2] = {};      // row-sums via MFMA x ones (same C/D layout as O)
  union { bf8v v; unsigned short u[8]; } onesu;
#pragma unroll
  for (int i = 0; i < 8; ++i) onesu.u[i] = 0x3F80;  // bf16 1.0
  const bf8v ones = onesu.v;

  // prologue: buf0 <- tile 0; issue tile-1 loads; certify buf0
  kv_write(0);
  kv_load(1);
  asm volatile("s_waitcnt lgkmcnt(0)" ::: "memory");
  __builtin_amdgcn_s_barrier();
  asm volatile("" ::: "memory");

  for (int kt = 0; kt < 32; ++kt) {
    const int c = kt & 1;
    if (kt < 31) {
      kv_write(c ^ 1);              // regs from kv_load(kt+1)
      if (kt < 30) kv_load(kt + 2); // issue; stays in flight across barriers
    }

    // ---- S^T = K . Q~^T (A = K[key32][d16], B = Q^T), ct-outer; exp2 + pack to dwords
    unsigned pk[2][2][8];  // [ct][qt][dw]; dw=2b,2b+1 hold quad rblock b (keys 8b+4hf+0..3)
#pragma unroll
    for (int ct = 0; ct < 2; ++ct) {
      f16v s[2] = {};
      __builtin_amdgcn_s_setprio(1);
#pragma unroll
      for (int ks = 0; ks < 4; ++ks) {
        bf8v ak = *(const bf8v*)&Kt[c][(ct * 32 + lq) * FSTR + ks * 16 + hf * 8];
        s[0] = __builtin_amdgcn_mfma_f32_32x32x16_bf16(ak, bq[0][ks], s[0], 0, 0, 0);
        s[1] = __builtin_amdgcn_mfma_f32_32x32x16_bf16(ak, bq[1][ks], s[1], 0, 0, 0);
      }
      __builtin_amdgcn_s_setprio(0);
#pragma unroll
      for (int qt = 0; qt < 2; ++qt)
#pragma unroll
        for (int dw = 0; dw < 8; ++dw)
          pk[ct][qt][dw] = pk2bf(exp2_hw(s[qt][2 * dw]), exp2_hw(s[qt][2 * dw + 1]));
    }

    // ---- O += P.V ; l += P.1 — A-frag built in-register via permlane32_swap.
    // kstep g covers keys 16g..16g+15: ct=g>>1; own quad rblock b0=(2g)&3, pair b1=b0+1.
    // After swap(a_i, bb_i): lanes<32 get {4g,4g+1}, lanes>=32 get {4g+2,4g+3}. 
#pragma unroll
    for (int g = 0; g < 4; ++g) {
      const int cg = g >> 1, b0 = (2 * g) & 3, b1 = (2 * g + 1) & 3;
      bf8v ap[2];
#pragma unroll
      for (int qt = 0; qt < 2; ++qt) {
        unsigned a0 = pk[cg][qt][2 * b0], a1 = pk[cg][qt][2 * b0 + 1];
        unsigned c0 = pk[cg][qt][2 * b1], c1 = pk[cg][qt][2 * b1 + 1];
        asm("v_permlane32_swap_b32 %0, %1" : "+v"(a0), "+v"(c0));
        asm("v_permlane32_swap_b32 %0, %1" : "+v"(a1), "+v"(c1));
        union { unsigned u[4]; bf8v v; } cc;
        cc.u[0] = a0; cc.u[1] = a1; cc.u[2] = c0; cc.u[3] = c1;
        ap[qt] = cc.v;
      }
      __builtin_amdgcn_s_setprio(1);
      acc_l[0] = __builtin_amdgcn_mfma_f32_32x32x16_bf16(ap[0], ones, acc_l[0], 0, 0, 0);
      acc_l[1] = __builtin_amdgcn_mfma_f32_32x32x16_bf16(ap[1], ones, acc_l[1], 0, 0, 0);
#pragma unroll
      for (int dt = 0; dt < 2; ++dt) {
        bf8v bv = *(const bf8v*)&Vt[c][(dt * 32 + lq) * FSTR + g * 16 + hf * 8];
        O[0][dt] = __builtin_amdgcn_mfma_f32_32x32x16_bf16(ap[0], bv, O[0][dt], 0, 0, 0);
        O[1][dt] = __builtin_amdgcn_mfma_f32_32x32x16_bf16(ap[1], bv, O[1][dt], 0, 0, 0);
      }
      __builtin_amdgcn_s_setprio(0);
    }

    asm volatile("s_waitcnt lgkmcnt(0)" ::: "memory");
    __builtin_amdgcn_s_barrier();   // single barrier per kt (v7 ledger)
    asm volatile("" ::: "memory");
  }

  // epilogue: 32x32 C/D row = (r&3) + 8*(r>>2) + 4*hf; acc_l aligned with O
#pragma unroll
  for (int qt = 0; qt < 2; ++qt) {
#pragma unroll
    for (int r = 0; r < 16; ++r) {
      float inv = 1.f / acc_l[qt][r];
      int row = q0 + wave * 64 + qt * 32 + (r & 3) + 8 * (r >> 2) + 4 * hf;
      size_t orow = ((size_t)b * 2048 + row) * 1024 + h * 64;
#pragma unroll
      for (int dt = 0; dt < 2; ++dt)
        y[orow + dt * 32 + lq] = f2bf(O[qt][dt][r] * inv);
    }
  }
}

// ---------------- launch ----------------
extern "C" void kernel_launch(void* const* d_in, const int* in_sizes, int n_in,
                              void* d_out, int out_size, void* d_ws, size_t ws_size,
                              hipStream_t stream) {
  (void)in_sizes; (void)n_in; (void)out_size; (void)ws_size;
  const float* x     = (const float*)d_in[0];
  const float* w_in  = (const float*)d_in[1];
  const float* b_in  = (const float*)d_in[2];
  const float* w_out = (const float*)d_in[3];
  const float* b_out = (const float*)d_in[4];

  // workspace layout (bf16 elements): qkv split into QK (8192x2048) + vtg
  unsigned short* xb  = (unsigned short*)d_ws;          // 8192x1024
  unsigned short* wiT = xb  + (size_t)8192 * 1024;      // 3072x1024 (w_in^T)
  unsigned short* woT = wiT + (size_t)3072 * 1024;      // 1024x1024 (w_out^T)
  unsigned short* qk  = woT + (size_t)1024 * 1024;      // 8192x2048 (Q|K)
  unsigned short* vtg = qk  + (size_t)8192 * 2048;      // 64x64x2048 (V^T)
  unsigned short* yb  = vtg + (size_t)64 * 64 * 2048;   // 8192x1024

  // cast + weight transpose fused (one launch)
  prep_kernel<<<12288, 256, 0, stream>>>(x, w_in, w_out, xb, wiT, woT);

  // qkv GEMM, 8-phase 256x256: Q,K -> qk (Q scaled by log2e); V -> vtg via LDS transpose
  gemm1_8ph<<<384, 512, 0, stream>>>(xb, wiT, b_in, qk, vtg, 1024, 12, L2E);
  // attention -> yb (32x32 MFMA, in-register P)
  flash_attn<<<512, 256, 0, stream>>>(qk, vtg, yb);
  // out = yb @ w_out + b_out; 256x128 tiles: grid 32x8 = 256 blocks = 1 round
  gemm2k<<<256, 512, 0, stream>>>(yb, woT, b_out, (float*)d_out, 1024, 1024, 8);
}

// Round 10
// 276.490 us; speedup vs baseline: 1.0554x; 1.0554x over previous
//
#include <hip/hip_runtime.h>
#include <hip/hip_bf16.h>
#include <stdint.h>

typedef __attribute__((ext_vector_type(8))) __bf16 bf8v;   // MFMA A/B frag: 8 bf16 = 4 VGPR
typedef __attribute__((ext_vector_type(4))) float f4v;     // MFMA C/D frag

#define L2E 1.44269504088896f

// fp32 -> bf16 round-to-nearest-even (bit pattern as ushort)
__device__ __forceinline__ unsigned short f2bf(float f) {
  union { float f; unsigned u; } v; v.f = f;
  unsigned r = v.u + 0x7fffu + ((v.u >> 16) & 1u);
  return (unsigned short)(r >> 16);
}

// pack two fp32 -> dword of two RNE bf16 (low = f0), HW v_cvt_pk_bf16_f32 path
__device__ __forceinline__ unsigned pk2bf(float f0, float f1) {
  union { __hip_bfloat162 h; unsigned u; } c;
  c.h = __float22bfloat162_rn(make_float2(f0, f1));
  return c.u;
}

// 2^x via v_exp_f32
__device__ __forceinline__ float exp2_hw(float x) {
  return __builtin_amdgcn_exp2f(x);
}

// async global->LDS, 16B per lane; LDS dest = wave-uniform base + lane*16
__device__ __forceinline__ void gl_lds16(const void* g, void* l) {
  __builtin_amdgcn_global_load_lds(
      (__attribute__((address_space(1))) void*)(g),
      (__attribute__((address_space(3))) void*)(l), 16, 0, 0);
}

// ---------------- fused prep: cast x -> bf16  +  weight transpose/cast ----------------
__global__ void prep_kernel(const float* __restrict__ x,
                            const float* __restrict__ w_in,
                            const float* __restrict__ w_out,
                            unsigned short* __restrict__ xb,
                            unsigned short* __restrict__ wiT,
                            unsigned short* __restrict__ woT) {
  __shared__ float tile[32][33];
  int bx = blockIdx.x;
  if (bx < 8192) {
    int i = bx * 256 + threadIdx.x;
    float4 v = ((const float4*)x)[i];
    ushort4 o;
    o.x = f2bf(v.x); o.y = f2bf(v.y); o.z = f2bf(v.z); o.w = f2bf(v.w);
    ((ushort4*)xb)[i] = o;
    return;
  }
  int idx = bx - 8192;              // 0..4095 -> (128 x, 32 y)
  int bxx = idx & 127, byy = idx >> 7;
  const float* in; unsigned short* out; int C, c0;
  if (bxx < 96) { in = w_in;  out = wiT; C = 3072; c0 = bxx * 32; }
  else          { in = w_out; out = woT; C = 1024; c0 = (bxx - 96) * 32; }
  int r0 = byy * 32;
  int tx = threadIdx.x & 31, ty = threadIdx.x >> 5;
#pragma unroll
  for (int j = 0; j < 4; ++j)
    tile[ty + 8 * j][tx] = in[(size_t)(r0 + ty + 8 * j) * C + c0 + tx];
  __syncthreads();
#pragma unroll
  for (int j = 0; j < 4; ++j)
    out[(size_t)(c0 + ty + 8 * j) * 1024 + r0 + tx] = f2bf(tile[tx][ty + 8 * j]);
}

// ---------------- GEMM1: 256x256, BK=64, 8-phase pipeline (r8-verified, scatter epilogue) ----------------
__global__ __launch_bounds__(512, 2) void gemm1_8ph(
    const unsigned short* __restrict__ A,
    const unsigned short* __restrict__ BT,
    const float* __restrict__ bias,
    unsigned short* __restrict__ qk,
    unsigned short* __restrict__ vtg,
    int K, int nbx, float scale) {
  __shared__ __align__(16) unsigned short As[2][256 * 64];
  __shared__ __align__(16) unsigned short Bs[2][256 * 64];
  const int tid = threadIdx.x;
  const int wave = tid >> 6, lane = tid & 63;
  const int lo = lane & 15, hi = lane >> 4;
  const int wm = wave >> 2, wn = wave & 3;   // 2M x 4N

  const int cpx = gridDim.x >> 3;
  const int s = (blockIdx.x & 7) * cpx + (blockIdx.x >> 3);
  const int by = s / nbx, bx = s - by * nbx;
  const int m0 = by * 256, n0 = bx * 256;

  const int srow = lane >> 3;
  const int scol = (((lane & 7) ^ (srow & 7)) * 8);
  const unsigned short* gA = A + (size_t)(m0 + wave * 8 + srow) * K + scol;
  const unsigned short* gB = BT + (size_t)(n0 + wave * 8 + srow) * K + scol;

  const int csw0 = ((hi ^ (lo & 7)) * 8);
  const int csw1 = (((4 + hi) ^ (lo & 7)) * 8);
  const int rA = wm * 128;   // + frag*16 + lo
  const int rB = wn * 64;    // + fn*16 + lo

  f4v acc[8][4] = {};
  const int nt = K >> 6;

  auto stageA = [&](int t, int buf, int half) {
    const unsigned short* g = gA + (size_t)(half * 128) * K + t * 64;
#pragma unroll
    for (int j = 0; j < 2; ++j)
      gl_lds16(g + (size_t)(j * 64) * K, &As[buf][(half * 128 + j * 64 + wave * 8) * 64]);
  };
  auto stageB = [&](int t, int buf, int half) {
    const unsigned short* g = gB + (size_t)(half * 128) * K + t * 64;
#pragma unroll
    for (int j = 0; j < 2; ++j)
      gl_lds16(g + (size_t)(j * 64) * K, &Bs[buf][(half * 128 + j * 64 + wave * 8) * 64]);
  };

  stageA(0, 0, 0); stageA(0, 0, 1);
  stageB(0, 0, 0); stageB(0, 0, 1);
  if (nt > 1) { stageB(1, 1, 0); stageB(1, 1, 1); }
  asm volatile("s_waitcnt vmcnt(4)" ::: "memory");
  __builtin_amdgcn_sched_barrier(0);
  __builtin_amdgcn_s_barrier();

  for (int t = 0; t < nt; ++t) {
    const int c = t & 1;
    bf8v b[4][2];
#pragma unroll
    for (int p = 0; p < 4; ++p) {
      if (p == 0) {
#pragma unroll
        for (int fn = 0; fn < 4; ++fn) {
          b[fn][0] = *(const bf8v*)&Bs[c][(rB + fn * 16 + lo) * 64 + csw0];
          b[fn][1] = *(const bf8v*)&Bs[c][(rB + fn * 16 + lo) * 64 + csw1];
        }
      }
      bf8v a[2][2];
#pragma unroll
      for (int i = 0; i < 2; ++i) {
        a[i][0] = *(const bf8v*)&As[c][(rA + (p * 2 + i) * 16 + lo) * 64 + csw0];
        a[i][1] = *(const bf8v*)&As[c][(rA + (p * 2 + i) * 16 + lo) * 64 + csw1];
      }
      if (p < 2) {
        if (t + 1 < nt) stageA(t + 1, c ^ 1, p);
      } else {
        if (t + 2 < nt) stageB(t + 2, c, p - 2);
      }
      if (p == 3 && t + 1 < nt) {
        if (t + 2 < nt) asm volatile("s_waitcnt vmcnt(4)" ::: "memory");
        else            asm volatile("s_waitcnt vmcnt(0)" ::: "memory");
        __builtin_amdgcn_sched_barrier(0);
      }
      __builtin_amdgcn_s_barrier();
      __builtin_amdgcn_s_setprio(1);
#pragma unroll
      for (int ks = 0; ks < 2; ++ks)
#pragma unroll
        for (int i = 0; i < 2; ++i)
#pragma unroll
          for (int fn = 0; fn < 4; ++fn)
            acc[p * 2 + i][fn] = __builtin_amdgcn_mfma_f32_16x16x32_bf16(
                a[i][ks], b[fn][ks], acc[p * 2 + i][fn], 0, 0, 0);
      __builtin_amdgcn_s_setprio(0);
      __builtin_amdgcn_s_barrier();
    }
  }

  // epilogue (r8 scatter form): Q/K -> qk (stride 2048), V -> vtg transposed
#pragma unroll
  for (int i = 0; i < 8; ++i) {
#pragma unroll
    for (int j = 0; j < 4; ++j) {
      const int col = n0 + wn * 64 + j * 16 + lo;
      const int row0 = m0 + wm * 128 + i * 16 + hi * 4;
      const float bb = bias[col];
      if (col < 2048) {
        const float sc = (col < 1024) ? scale : 1.0f;
#pragma unroll
        for (int r = 0; r < 4; ++r)
          qk[(size_t)(row0 + r) * 2048 + col] = f2bf((acc[i][j][r] + bb) * sc);
      } else {
        const int d = (col - 2048) & 63, hh = (col - 2048) >> 6;
        const int bbt = row0 >> 11, tok = row0 & 2047;
        ushort4 o;
        o.x = f2bf(acc[i][j][0] + bb);
        o.y = f2bf(acc[i][j][1] + bb);
        o.z = f2bf(acc[i][j][2] + bb);
        o.w = f2bf(acc[i][j][3] + bb);
        *(ushort4*)&vtg[((((size_t)bbt * 16 + hh) * 64 + d) * 2048) + tok] = o;
      }
    }
  }
}

// ---------------- GEMM2: 64x128 tile, BK=32, fp32 out — round-0 occupancy-4 config ----------------
// 4 waves, 16 KB LDS single-buffered, __launch_bounds__(256,4) -> ~16 waves/CU;
// grid (8,128) = 1024 blocks fills the machine at 4 blocks/CU in one round.
// A/B vs r8's 1-block/CU gemm2k isolates the occupancy lever for the GEMM class.
__global__ __launch_bounds__(256, 4) void gemm_bt_sm(
    const unsigned short* __restrict__ A,
    const unsigned short* __restrict__ BT,
    const float* __restrict__ bias,
    float* __restrict__ C,
    int M, int N, int K) {
  __shared__ __align__(16) unsigned short As[64 * 32];   // [m][k]
  __shared__ __align__(16) unsigned short Bs[128 * 32];  // [n][k]
  const int tid = threadIdx.x;
  const int wave = tid >> 6, lane = tid & 63;
  const int lo = lane & 15, hi = lane >> 4;
  const int m0 = blockIdx.y * 64, n0 = blockIdx.x * 128;
  const int wm = (wave >> 1) * 32, wn = (wave & 1) * 64;

  f4v acc[2][4] = {};

  const int srow = lane >> 2;
  const int scol = (lane & 3) * 8;

  for (int k0 = 0; k0 < K; k0 += 32) {
    gl_lds16(A + (size_t)(m0 + wave * 16 + srow) * K + k0 + scol,
             &As[(wave * 16) * 32]);
#pragma unroll
    for (int p = 0; p < 2; ++p) {
      int r = p * 64 + wave * 16 + srow;
      gl_lds16(BT + (size_t)(n0 + r) * K + k0 + scol,
               &Bs[(p * 64 + wave * 16) * 32]);
    }
    __syncthreads();
    bf8v a[2], b[4];
#pragma unroll
    for (int i = 0; i < 2; ++i)
      a[i] = *(const bf8v*)&As[(wm + i * 16 + lo) * 32 + hi * 8];
#pragma unroll
    for (int j = 0; j < 4; ++j)
      b[j] = *(const bf8v*)&Bs[(wn + j * 16 + lo) * 32 + hi * 8];
#pragma unroll
    for (int i = 0; i < 2; ++i)
#pragma unroll
      for (int j = 0; j < 4; ++j)
        acc[i][j] = __builtin_amdgcn_mfma_f32_16x16x32_bf16(a[i], b[j], acc[i][j], 0, 0, 0);
    __syncthreads();
  }

#pragma unroll
  for (int i = 0; i < 2; ++i) {
#pragma unroll
    for (int r = 0; r < 4; ++r) {
      int row = m0 + wm + i * 16 + hi * 4 + r;
#pragma unroll
      for (int j = 0; j < 4; ++j) {
        int col = n0 + wn + j * 16 + lo;
        C[(size_t)row * N + col] = acc[i][j][r] + bias[col];
      }
    }
  }
}

// ---------------- flash attention v7 (r8 byte-identical; QK stride 2048) ----------------
#define FSTR 72   // LDS row stride (shorts): 64 payload + 8 pad

__global__ __launch_bounds__(256, 2) void flash_attn(
    const unsigned short* __restrict__ qk,    // [8192][2048]: Q cols 0..1023, K cols 1024..2047
    const unsigned short* __restrict__ vtg,   // [b*16+h][64][2048]
    unsigned short* __restrict__ y) {
  __shared__ __align__(16) unsigned short Ps[256 * FSTR];   // Q stage, then P tile [q][key]
  __shared__ __align__(16) unsigned short Kt[2][64 * FSTR]; // K tiles [key][d], dbuf
  __shared__ __align__(16) unsigned short Vt[2][64 * FSTR]; // V^T tiles [d][key], dbuf
  const int tid = threadIdx.x;
  const int wave = tid >> 6, lane = tid & 63;
  const int lo = lane & 15, hi = lane >> 4;

  const int lin = blockIdx.x;
  const int swz = (lin & 7) * 64 + (lin >> 3);
  const int q0 = (swz & 7) << 8;
  const int h  = (swz >> 3) & 15;
  const int b  = swz >> 7;

  const size_t base = (size_t)b * 2048 * 2048;
  const int qoff = h * 64, koff = 1024 + h * 64;
  const unsigned short* vsrc = vtg + (size_t)(b * 16 + h) * 64 * 2048;

  const int m_st = tid >> 3, c_st = tid & 7;
  const unsigned short* kg = qk + base + koff;
  float4 rk0, rk1, rv0, rv1;
  auto kv_load = [&](int kt) {
    const int mb = kt * 64;
    rk0 = *(const float4*)(kg + (size_t)(mb + m_st) * 2048 + c_st * 8);
    rk1 = *(const float4*)(kg + (size_t)(mb + m_st + 32) * 2048 + c_st * 8);
    rv0 = *(const float4*)(vsrc + (size_t)m_st * 2048 + mb + c_st * 8);
    rv1 = *(const float4*)(vsrc + (size_t)(m_st + 32) * 2048 + mb + c_st * 8);
  };
  auto kv_write = [&](int buf) {
    *(float4*)&Kt[buf][m_st * FSTR + c_st * 8] = rk0;
    *(float4*)&Kt[buf][(m_st + 32) * FSTR + c_st * 8] = rk1;
    *(float4*)&Vt[buf][m_st * FSTR + c_st * 8] = rv0;
    *(float4*)&Vt[buf][(m_st + 32) * FSTR + c_st * 8] = rv1;
  };

  kv_load(0);

#pragma unroll
  for (int i = 0; i < 8; ++i) {
    int cid = i * 256 + tid;
    int m = cid >> 3, c = cid & 7;
    *(float4*)&Ps[m * FSTR + c * 8] =
        *(const float4*)(qk + base + (size_t)(q0 + m) * 2048 + qoff + c * 8);
  }
  __syncthreads();
  bf8v bq[4][2];  // [qt][ks]
#pragma unroll
  for (int qt = 0; qt < 4; ++qt)
#pragma unroll
    for (int ks = 0; ks < 2; ++ks)
      bq[qt][ks] = *(const bf8v*)&Ps[(wave * 64 + qt * 16 + lo) * FSTR + ks * 32 + hi * 8];

  f4v O[4][4] = {};       // [qt][dt]
  f4v acc_l[4] = {};      // row-sums via MFMA x ones
  union { bf8v v; unsigned short u[8]; } onesu;
#pragma unroll
  for (int i = 0; i < 8; ++i) onesu.u[i] = 0x3F80;  // bf16 1.0
  const bf8v ones = onesu.v;

  kv_write(0);
  kv_load(1);
  asm volatile("s_waitcnt lgkmcnt(0)" ::: "memory");
  __builtin_amdgcn_s_barrier();
  asm volatile("" ::: "memory");

  for (int kt = 0; kt < 32; ++kt) {
    const int c = kt & 1;
    if (kt < 31) {
      kv_write(c ^ 1);
      if (kt < 30) kv_load(kt + 2);
    }

#pragma unroll
    for (int ct = 0; ct < 4; ++ct) {
      f4v s[4] = {{}, {}, {}, {}};
      __builtin_amdgcn_s_setprio(1);
#pragma unroll
      for (int ks = 0; ks < 2; ++ks) {
        bf8v ak = *(const bf8v*)&Kt[c][(ct * 16 + lo) * FSTR + ks * 32 + hi * 8];
#pragma unroll
        for (int qt = 0; qt < 4; ++qt)
          s[qt] = __builtin_amdgcn_mfma_f32_16x16x32_bf16(ak, bq[qt][ks], s[qt], 0, 0, 0);
      }
      __builtin_amdgcn_s_setprio(0);
#pragma unroll
      for (int qt = 0; qt < 4; ++qt) {
        float p0 = exp2_hw(s[qt][0]), p1 = exp2_hw(s[qt][1]);
        float p2 = exp2_hw(s[qt][2]), p3 = exp2_hw(s[qt][3]);
        uint2 w; w.x = pk2bf(p0, p1); w.y = pk2bf(p2, p3);
        *(uint2*)&Ps[(wave * 64 + qt * 16 + lo) * FSTR + ct * 16 + hi * 4] = w;
      }
    }

#pragma unroll
    for (int ks = 0; ks < 2; ++ks) {
      bf8v ap[4];
#pragma unroll
      for (int qt = 0; qt < 4; ++qt)
        ap[qt] = *(const bf8v*)&Ps[(wave * 64 + qt * 16 + lo) * FSTR + ks * 32 + hi * 8];
      __builtin_amdgcn_s_setprio(1);
#pragma unroll
      for (int qt = 0; qt < 4; ++qt)
        acc_l[qt] = __builtin_amdgcn_mfma_f32_16x16x32_bf16(ap[qt], ones, acc_l[qt], 0, 0, 0);
#pragma unroll
      for (int dt = 0; dt < 4; ++dt) {
        bf8v bv = *(const bf8v*)&Vt[c][(dt * 16 + lo) * FSTR + ks * 32 + hi * 8];
#pragma unroll
        for (int qt = 0; qt < 4; ++qt)
          O[qt][dt] = __builtin_amdgcn_mfma_f32_16x16x32_bf16(ap[qt], bv, O[qt][dt], 0, 0, 0);
      }
      __builtin_amdgcn_s_setprio(0);
    }

    asm volatile("s_waitcnt lgkmcnt(0)" ::: "memory");
    __builtin_amdgcn_s_barrier();
    asm volatile("" ::: "memory");
  }

#pragma unroll
  for (int qt = 0; qt < 4; ++qt) {
#pragma unroll
    for (int r = 0; r < 4; ++r) {
      float inv = 1.f / acc_l[qt][r];
      int row = q0 + wave * 64 + qt * 16 + hi * 4 + r;
      size_t orow = ((size_t)b * 2048 + row) * 1024 + h * 64;
#pragma unroll
      for (int dt = 0; dt < 4; ++dt)
        y[orow + dt * 16 + lo] = f2bf(O[qt][dt][r] * inv);
    }
  }
}

// ---------------- launch ----------------
extern "C" void kernel_launch(void* const* d_in, const int* in_sizes, int n_in,
                              void* d_out, int out_size, void* d_ws, size_t ws_size,
                              hipStream_t stream) {
  (void)in_sizes; (void)n_in; (void)out_size; (void)ws_size;
  const float* x     = (const float*)d_in[0];
  const float* w_in  = (const float*)d_in[1];
  const float* b_in  = (const float*)d_in[2];
  const float* w_out = (const float*)d_in[3];
  const float* b_out = (const float*)d_in[4];

  // workspace layout (bf16 elements): qkv split into QK (8192x2048) + vtg
  unsigned short* xb  = (unsigned short*)d_ws;          // 8192x1024
  unsigned short* wiT = xb  + (size_t)8192 * 1024;      // 3072x1024 (w_in^T)
  unsigned short* woT = wiT + (size_t)3072 * 1024;      // 1024x1024 (w_out^T)
  unsigned short* qk  = woT + (size_t)1024 * 1024;      // 8192x2048 (Q|K)
  unsigned short* vtg = qk  + (size_t)8192 * 2048;      // 64x64x2048 (V^T)
  unsigned short* yb  = vtg + (size_t)64 * 64 * 2048;   // 8192x1024

  // cast + weight transpose fused (one launch)
  prep_kernel<<<12288, 256, 0, stream>>>(x, w_in, w_out, xb, wiT, woT);

  // qkv GEMM, 8-phase 256x256: Q,K -> qk (Q scaled by log2e); V -> vtg transposed
  gemm1_8ph<<<384, 512, 0, stream>>>(xb, wiT, b_in, qk, vtg, 1024, 12, L2E);
  // attention -> yb
  flash_attn<<<512, 256, 0, stream>>>(qk, vtg, yb);
  // out = yb @ w_out + b_out — occupancy-4 64x128 config, grid 1024 blocks
  gemm_bt_sm<<<dim3(8, 128), 256, 0, stream>>>(yb, woT, b_out, (float*)d_out,
                                               8192, 1024, 1024);
}